// Round 1
// baseline (1456.367 us; speedup 1.0000x reference)
//
#include <hip/hip_runtime.h>

// Problem constants
#define BSZ 8
#define NH 12
#define LSEQ 1024
#define DMODEL 768
#define DHEAD 64
#define OUT_ELEMS 6291456   // 8*1024*768
#define ATTN_ELEMS 8388608  // 8*1024*1024

__device__ __forceinline__ float wred(float v) {
    v += __shfl_xor(v, 1);
    v += __shfl_xor(v, 2);
    v += __shfl_xor(v, 4);
    v += __shfl_xor(v, 8);
    v += __shfl_xor(v, 16);
    v += __shfl_xor(v, 32);
    return v;
}

// C = A @ W^T + bias, A [8192x768], W [768x768] row-major [out,in].
// Output scattered to head layout [B,H,L,64]. blockIdx.z: 0 -> Q proj, 1 -> K proj.
__global__ __launch_bounds__(256) void proj_kernel(
    const float* __restrict__ qin, const float* __restrict__ kin,
    const float* __restrict__ Wq, const float* __restrict__ bq,
    const float* __restrict__ Wk, const float* __restrict__ bk,
    float* __restrict__ ws) {
    const float* A; const float* W; const float* bias; float* out;
    if (blockIdx.z == 0) { A = qin; W = Wq; bias = bq; out = ws; }
    else                 { A = kin; W = Wk; bias = bk; out = ws + OUT_ELEMS; }

    __shared__ float As[16][68];  // [k][m], pad 68 keeps float4 alignment
    __shared__ float Bs[16][68];  // [k][n]

    const int t  = threadIdx.x;
    const int m0 = blockIdx.y * 64;
    const int n0 = blockIdx.x * 64;
    const int lr = t >> 2;          // 0..63 row within tile
    const int lc = (t & 3) * 4;     // 0,4,8,12 k offset
    const int tx = t & 15, ty = t >> 4;

    float acc[4][4] = {};

    for (int k0 = 0; k0 < DMODEL; k0 += 16) {
        float4 av = *(const float4*)&A[(size_t)(m0 + lr) * DMODEL + k0 + lc];
        float4 wv = *(const float4*)&W[(size_t)(n0 + lr) * DMODEL + k0 + lc];
        __syncthreads();
        As[lc + 0][lr] = av.x; As[lc + 1][lr] = av.y; As[lc + 2][lr] = av.z; As[lc + 3][lr] = av.w;
        Bs[lc + 0][lr] = wv.x; Bs[lc + 1][lr] = wv.y; Bs[lc + 2][lr] = wv.z; Bs[lc + 3][lr] = wv.w;
        __syncthreads();
#pragma unroll
        for (int kk = 0; kk < 16; ++kk) {
            float4 a4 = *(const float4*)&As[kk][ty * 4];
            float4 b4 = *(const float4*)&Bs[kk][tx * 4];
            float ar[4] = {a4.x, a4.y, a4.z, a4.w};
            float br[4] = {b4.x, b4.y, b4.z, b4.w};
#pragma unroll
            for (int i = 0; i < 4; ++i)
#pragma unroll
                for (int j = 0; j < 4; ++j) acc[i][j] += ar[i] * br[j];
        }
    }

    const int h = n0 >> 6;                 // n-tile == one head (64-aligned)
    float4 bias4 = *(const float4*)&bias[n0 + tx * 4];
#pragma unroll
    for (int i = 0; i < 4; ++i) {
        int m = m0 + ty * 4 + i;
        int bb = m >> 10, l = m & 1023;
        float4 o;
        o.x = acc[i][0] + bias4.x;
        o.y = acc[i][1] + bias4.y;
        o.z = acc[i][2] + bias4.z;
        o.w = acc[i][3] + bias4.w;
        *(float4*)&out[(((size_t)bb * NH + h) * LSEQ + l) * DHEAD + tx * 4] = o;
    }
}

// Fused scores + sparsemax + head-mean. One block per (b, 8 q-rows).
__global__ __launch_bounds__(256) void attn_kernel(
    const float* __restrict__ Qh, const float* __restrict__ Kh,
    float* __restrict__ attn_out) {
    __shared__ float S[8][1024];      // 32 KB score rows
    __shared__ float Ks[64][68];      // 17 KB K tile, pad 68 for float4
    __shared__ float Qs[8][64];       // 2 KB

    const int t = threadIdx.x;
    const int lane = t & 63;
    const int w = t >> 6;             // wave 0..3
    const int b = blockIdx.y;
    const int q0 = blockIdx.x * 8;

    float acc[32];
#pragma unroll
    for (int j = 0; j < 32; ++j) acc[j] = 0.f;

    for (int h = 0; h < NH; ++h) {
        const float* Qb = Qh + (((size_t)b * NH + h) * LSEQ + q0) * DHEAD;
        const float* Kb = Kh + (((size_t)b * NH + h) * LSEQ) * DHEAD;

        __syncthreads();
        if (t < 128) {
            *(float4*)&Qs[t >> 4][(t & 15) * 4] = *(const float4*)&Qb[t * 4];
        }

        // scores: 16 chunks of 64 kv-columns
        for (int cc = 0; cc < 16; ++cc) {
            __syncthreads();   // prev chunk's compute done (and Qs visible on cc==0)
#pragma unroll
            for (int i = 0; i < 4; ++i) {
                float4 kv = *(const float4*)&Kb[cc * 4096 + i * 1024 + t * 4];
                *(float4*)&Ks[i * 16 + (t >> 4)][(t & 15) * 4] = kv;
            }
            __syncthreads();
            const int c = lane;
            const int r0 = w * 2;
            float a0 = 0.f, a1 = 0.f;
#pragma unroll
            for (int d4 = 0; d4 < 64; d4 += 4) {
                float4 kv = *(const float4*)&Ks[c][d4];
                float4 qa = *(const float4*)&Qs[r0][d4];
                float4 qb = *(const float4*)&Qs[r0 + 1][d4];
                a0 += qa.x * kv.x + qa.y * kv.y + qa.z * kv.z + qa.w * kv.w;
                a1 += qb.x * kv.x + qb.y * kv.y + qb.z * kv.z + qb.w * kv.w;
            }
            S[r0][cc * 64 + c]     = a0 * 0.125f;   // 1/sqrt(64)
            S[r0 + 1][cc * 64 + c] = a1 * 0.125f;
        }
        __syncthreads();

        // sparsemax via Michelot projection: wave w owns rows 2w, 2w+1
#pragma unroll
        for (int rr = 0; rr < 2; ++rr) {
            const int r = w * 2 + rr;
            float z[16];
#pragma unroll
            for (int j = 0; j < 16; ++j) z[j] = S[r][lane + 64 * j];
            float s0 = 0.f;
#pragma unroll
            for (int j = 0; j < 16; ++j) s0 += z[j];
            float tau = (wred(s0) - 1.0f) * (1.0f / 1024.0f);
            float prev = 1024.0f;
            for (int it = 0; it < 128; ++it) {
                float s = 0.f, c2 = 0.f;
#pragma unroll
                for (int j = 0; j < 16; ++j) {
                    if (z[j] > tau) { s += z[j]; c2 += 1.0f; }
                }
                s = wred(s); c2 = wred(c2);
                if (c2 == prev) break;   // support stable -> tau is exact
                tau = (s - 1.0f) / c2;
                prev = c2;
            }
#pragma unroll
            for (int j = 0; j < 16; ++j) {
                float p = z[j] - tau;
                S[r][lane + 64 * j] = p > 0.f ? p : 0.f;
            }
        }
        __syncthreads();

        // head-mean accumulate into registers
#pragma unroll
        for (int j = 0; j < 32; ++j) {
            int f = j * 256 + t;
            acc[j] += S[f >> 10][f & 1023] * (1.0f / 12.0f);
        }
    }

    float* ao = attn_out + ((size_t)b * LSEQ + q0) * LSEQ;
#pragma unroll
    for (int j = 0; j < 32; ++j) ao[j * 256 + t] = acc[j];
}

// out[b] = attn[b] (1024x1024) @ v[b] (1024x768)
__global__ __launch_bounds__(256) void out_gemm(
    const float* __restrict__ attn, const float* __restrict__ v,
    float* __restrict__ out) {
    const int b = blockIdx.z;
    const float* A  = attn + (size_t)b * LSEQ * LSEQ;
    const float* Bv = v    + (size_t)b * LSEQ * DMODEL;
    float* C        = out  + (size_t)b * LSEQ * DMODEL;

    __shared__ float As[16][68];  // [k][m]
    __shared__ float Bs[16][68];  // [k][n]

    const int t  = threadIdx.x;
    const int m0 = blockIdx.y * 64;
    const int n0 = blockIdx.x * 64;
    const int lr = t >> 2;
    const int lc = (t & 3) * 4;
    const int tx = t & 15, ty = t >> 4;

    float acc[4][4] = {};

    for (int k0 = 0; k0 < LSEQ; k0 += 16) {
        float4 av = *(const float4*)&A[(size_t)(m0 + lr) * LSEQ + k0 + lc];
        float4 bv = *(const float4*)&Bv[(size_t)(k0 + (t >> 4)) * DMODEL + n0 + (t & 15) * 4];
        __syncthreads();
        As[lc + 0][lr] = av.x; As[lc + 1][lr] = av.y; As[lc + 2][lr] = av.z; As[lc + 3][lr] = av.w;
        *(float4*)&Bs[t >> 4][(t & 15) * 4] = bv;
        __syncthreads();
#pragma unroll
        for (int kk = 0; kk < 16; ++kk) {
            float4 a4 = *(const float4*)&As[kk][ty * 4];
            float4 b4 = *(const float4*)&Bs[kk][tx * 4];
            float ar[4] = {a4.x, a4.y, a4.z, a4.w};
            float br[4] = {b4.x, b4.y, b4.z, b4.w};
#pragma unroll
            for (int i = 0; i < 4; ++i)
#pragma unroll
                for (int j = 0; j < 4; ++j) acc[i][j] += ar[i] * br[j];
        }
    }

#pragma unroll
    for (int i = 0; i < 4; ++i) {
        float4 o;
        o.x = acc[i][0]; o.y = acc[i][1]; o.z = acc[i][2]; o.w = acc[i][3];
        *(float4*)&C[(size_t)(m0 + ty * 4 + i) * DMODEL + n0 + tx * 4] = o;
    }
}

extern "C" void kernel_launch(void* const* d_in, const int* in_sizes, int n_in,
                              void* d_out, int out_size, void* d_ws, size_t ws_size,
                              hipStream_t stream) {
    const float* q  = (const float*)d_in[0];
    const float* k  = (const float*)d_in[1];
    const float* v  = (const float*)d_in[2];
    const float* Wq = (const float*)d_in[3];
    const float* bq = (const float*)d_in[4];
    const float* Wk = (const float*)d_in[5];
    const float* bk = (const float*)d_in[6];

    float* out  = (float*)d_out;            // [8,1024,768]
    float* attn = out + OUT_ELEMS;          // [8,1024,1024]
    float* ws   = (float*)d_ws;             // Qh then Kh, each [8,12,1024,64] (48 MB total)

    // 1) Q/K projections into head layout
    hipLaunchKernelGGL(proj_kernel, dim3(12, 128, 2), dim3(256), 0, stream,
                       q, k, Wq, bq, Wk, bk, ws);
    // 2) fused scores + sparsemax + head-mean -> attn output
    hipLaunchKernelGGL(attn_kernel, dim3(128, 8), dim3(256), 0, stream,
                       ws, ws + OUT_ELEMS, attn);
    // 3) output = attn @ v
    hipLaunchKernelGGL(out_gemm, dim3(12, 16, 8), dim3(256), 0, stream,
                       attn, v, out);
}

// Round 2
// 856.662 us; speedup vs baseline: 1.7000x; 1.7000x over previous
//
#include <hip/hip_runtime.h>

// Problem constants
#define BSZ 8
#define NH 12
#define LSEQ 1024
#define DMODEL 768
#define DHEAD 64
#define OUT_ELEMS 6291456   // 8*1024*768
#define ATTN_ELEMS 8388608  // 8*1024*1024

typedef __attribute__((ext_vector_type(8))) short short8;   // 8 x bf16 (4 VGPRs)
typedef __attribute__((ext_vector_type(4))) float f32x4;

__device__ __forceinline__ float wred(float v) {
    v += __shfl_xor(v, 1);
    v += __shfl_xor(v, 2);
    v += __shfl_xor(v, 4);
    v += __shfl_xor(v, 8);
    v += __shfl_xor(v, 16);
    v += __shfl_xor(v, 32);
    return v;
}

__device__ __forceinline__ unsigned short f2bf(float x) {
    union { float f; unsigned u; } c; c.f = x;
    unsigned r = (c.u + 0x7FFF + ((c.u >> 16) & 1)) >> 16;   // RNE
    return (unsigned short)r;
}
__device__ __forceinline__ float bf2f(unsigned short h) {
    union { float f; unsigned u; } c; c.u = ((unsigned)h) << 16;
    return c.f;
}

// C = A @ W^T + bias, A [8192x768], W [768x768] row-major [out,in].
// Output written as SPLIT-BF16 (hi + lo planes) in head layout [B,H,L,64].
// blockIdx.z: 0 -> Q proj (planes 0,1), 1 -> K proj (planes 2,3).
__global__ __launch_bounds__(256) void proj_kernel(
    const float* __restrict__ qin, const float* __restrict__ kin,
    const float* __restrict__ Wq, const float* __restrict__ bq,
    const float* __restrict__ Wk, const float* __restrict__ bk,
    unsigned short* __restrict__ ws) {
    const float* A; const float* W; const float* bias;
    unsigned short* hi; unsigned short* lo;
    if (blockIdx.z == 0) { A = qin; W = Wq; bias = bq; hi = ws;                 lo = ws + OUT_ELEMS; }
    else                 { A = kin; W = Wk; bias = bk; hi = ws + 2*OUT_ELEMS;  lo = ws + 3*OUT_ELEMS; }

    __shared__ float As[16][68];  // [k][m], pad 68 keeps float4 alignment
    __shared__ float Bs[16][68];  // [k][n]

    const int t  = threadIdx.x;
    const int m0 = blockIdx.y * 64;
    const int n0 = blockIdx.x * 64;
    const int lr = t >> 2;          // 0..63 row within tile
    const int lc = (t & 3) * 4;     // 0,4,8,12 k offset
    const int tx = t & 15, ty = t >> 4;

    float acc[4][4] = {};

    for (int k0 = 0; k0 < DMODEL; k0 += 16) {
        float4 av = *(const float4*)&A[(size_t)(m0 + lr) * DMODEL + k0 + lc];
        float4 wv = *(const float4*)&W[(size_t)(n0 + lr) * DMODEL + k0 + lc];
        __syncthreads();
        As[lc + 0][lr] = av.x; As[lc + 1][lr] = av.y; As[lc + 2][lr] = av.z; As[lc + 3][lr] = av.w;
        Bs[lc + 0][lr] = wv.x; Bs[lc + 1][lr] = wv.y; Bs[lc + 2][lr] = wv.z; Bs[lc + 3][lr] = wv.w;
        __syncthreads();
#pragma unroll
        for (int kk = 0; kk < 16; ++kk) {
            float4 a4 = *(const float4*)&As[kk][ty * 4];
            float4 b4 = *(const float4*)&Bs[kk][tx * 4];
            float ar[4] = {a4.x, a4.y, a4.z, a4.w};
            float br[4] = {b4.x, b4.y, b4.z, b4.w};
#pragma unroll
            for (int i = 0; i < 4; ++i)
#pragma unroll
                for (int j = 0; j < 4; ++j) acc[i][j] += ar[i] * br[j];
        }
    }

    const int h = n0 >> 6;                 // n-tile == one head (64-aligned)
    float4 bias4 = *(const float4*)&bias[n0 + tx * 4];
#pragma unroll
    for (int i = 0; i < 4; ++i) {
        int m = m0 + ty * 4 + i;
        int bb = m >> 10, l = m & 1023;
        float o[4];
        o[0] = acc[i][0] + bias4.x;
        o[1] = acc[i][1] + bias4.y;
        o[2] = acc[i][2] + bias4.z;
        o[3] = acc[i][3] + bias4.w;
        ushort4 h4, l4;
        unsigned short hh;
        hh = f2bf(o[0]); h4.x = hh; l4.x = f2bf(o[0] - bf2f(hh));
        hh = f2bf(o[1]); h4.y = hh; l4.y = f2bf(o[1] - bf2f(hh));
        hh = f2bf(o[2]); h4.z = hh; l4.z = f2bf(o[2] - bf2f(hh));
        hh = f2bf(o[3]); h4.w = hh; l4.w = f2bf(o[3] - bf2f(hh));
        size_t idx = (((size_t)bb * NH + h) * LSEQ + l) * DHEAD + tx * 4;
        *(ushort4*)&hi[idx] = h4;
        *(ushort4*)&lo[idx] = l4;
    }
}

// Fused scores (split-bf16 MFMA) + sparsemax + head-mean.
// One block per (b, 16 q-rows). 4 waves; wave w owns kv-columns [w*256, w*256+256).
__global__ __launch_bounds__(256, 2) void attn_kernel(
    const unsigned short* __restrict__ ws, float* __restrict__ attn_out) {
    __shared__ float S[16 * 1024];    // 64 KB score tile

    const unsigned short* Qhi = ws;
    const unsigned short* Qlo = ws + OUT_ELEMS;
    const unsigned short* Khi = ws + 2 * OUT_ELEMS;
    const unsigned short* Klo = ws + 3 * OUT_ELEMS;

    const int t = threadIdx.x;
    const int lane = t & 63;
    const int w = t >> 6;
    const int b = blockIdx.y;
    const int q0 = blockIdx.x * 16;

    const int mrow = lane & 15;   // A-operand m / B-operand n index
    const int quad = lane >> 4;   // k = quad*8 + j

    f32x4 acc[16];
#pragma unroll
    for (int j = 0; j < 16; ++j) acc[j] = (f32x4){0.f, 0.f, 0.f, 0.f};

    for (int h = 0; h < NH; ++h) {
        const size_t hb = ((size_t)b * NH + h) * (LSEQ * DHEAD);

        // A fragments: Q rows q0..q0+15, both d-halves, hi and lo planes
        const size_t aoff = hb + (size_t)(q0 + mrow) * DHEAD + quad * 8;
        short8 ah0 = *(const short8*)(Qhi + aoff);
        short8 ah1 = *(const short8*)(Qhi + aoff + 32);
        short8 al0 = *(const short8*)(Qlo + aoff);
        short8 al1 = *(const short8*)(Qlo + aoff + 32);

        __syncthreads();   // previous head's S reads complete before overwrite

#pragma unroll 4
        for (int nt = 0; nt < 16; ++nt) {
            const int n0 = w * 256 + nt * 16;
            const size_t boff = hb + (size_t)(n0 + mrow) * DHEAD + quad * 8;
            short8 bh0 = *(const short8*)(Khi + boff);
            short8 bh1 = *(const short8*)(Khi + boff + 32);
            short8 bl0 = *(const short8*)(Klo + boff);
            short8 bl1 = *(const short8*)(Klo + boff + 32);
            f32x4 d = {0.f, 0.f, 0.f, 0.f};
            d = __builtin_amdgcn_mfma_f32_16x16x32_bf16(al0, bh0, d, 0, 0, 0);
            d = __builtin_amdgcn_mfma_f32_16x16x32_bf16(ah0, bl0, d, 0, 0, 0);
            d = __builtin_amdgcn_mfma_f32_16x16x32_bf16(ah0, bh0, d, 0, 0, 0);
            d = __builtin_amdgcn_mfma_f32_16x16x32_bf16(al1, bh1, d, 0, 0, 0);
            d = __builtin_amdgcn_mfma_f32_16x16x32_bf16(ah1, bl1, d, 0, 0, 0);
            d = __builtin_amdgcn_mfma_f32_16x16x32_bf16(ah1, bh1, d, 0, 0, 0);
            // D layout: col = lane&15, row = quad*4 + reg  [m89/m91-verified]
#pragma unroll
            for (int reg = 0; reg < 4; ++reg)
                S[(quad * 4 + reg) * 1024 + n0 + mrow] = d[reg] * 0.125f;
        }
        __syncthreads();

        // sparsemax (Michelot projection) — wave w owns rows 4w..4w+3
#pragma unroll
        for (int rr = 0; rr < 4; ++rr) {
            const int r = w * 4 + rr;
            float z[16];
#pragma unroll
            for (int j = 0; j < 16; ++j) z[j] = S[r * 1024 + lane + 64 * j];
            float s0 = 0.f;
#pragma unroll
            for (int j = 0; j < 16; ++j) s0 += z[j];
            float tau = (wred(s0) - 1.0f) * (1.0f / 1024.0f);
            float prev = 1024.0f;
            for (int it = 0; it < 64; ++it) {
                float s = 0.f, c2 = 0.f;
#pragma unroll
                for (int j = 0; j < 16; ++j) {
                    if (z[j] > tau) { s += z[j]; c2 += 1.0f; }
                }
                s = wred(s); c2 = wred(c2);
                if (c2 == prev) break;   // support stable -> tau exact
                tau = (s - 1.0f) / c2;
                prev = c2;
            }
#pragma unroll
            for (int j = 0; j < 16; ++j) {
                float p = z[j] - tau;
                S[r * 1024 + lane + 64 * j] = p > 0.f ? p : 0.f;
            }
        }
        __syncthreads();

        // head-mean accumulate: thread t owns float4-column t across all 16 rows
#pragma unroll
        for (int j = 0; j < 16; ++j) {
            f32x4 vv = *(const f32x4*)&S[j * 1024 + t * 4];
            acc[j] += vv;
        }
    }

    float* ao = attn_out + ((size_t)b * LSEQ + q0) * LSEQ;
#pragma unroll
    for (int j = 0; j < 16; ++j) {
        f32x4 o = acc[j] * (1.0f / 12.0f);
        *(f32x4*)&ao[(size_t)j * LSEQ + t * 4] = o;
    }
}

// out[b] = attn[b] (1024x1024) @ v[b] (1024x768)
__global__ __launch_bounds__(256) void out_gemm(
    const float* __restrict__ attn, const float* __restrict__ v,
    float* __restrict__ out) {
    const int b = blockIdx.z;
    const float* A  = attn + (size_t)b * LSEQ * LSEQ;
    const float* Bv = v    + (size_t)b * LSEQ * DMODEL;
    float* C        = out  + (size_t)b * LSEQ * DMODEL;

    __shared__ float As[16][68];  // [k][m]
    __shared__ float Bs[16][68];  // [k][n]

    const int t  = threadIdx.x;
    const int m0 = blockIdx.y * 64;
    const int n0 = blockIdx.x * 64;
    const int lr = t >> 2;
    const int lc = (t & 3) * 4;
    const int tx = t & 15, ty = t >> 4;

    float acc[4][4] = {};

    for (int k0 = 0; k0 < LSEQ; k0 += 16) {
        float4 av = *(const float4*)&A[(size_t)(m0 + lr) * LSEQ + k0 + lc];
        float4 bv = *(const float4*)&Bv[(size_t)(k0 + (t >> 4)) * DMODEL + n0 + (t & 15) * 4];
        __syncthreads();
        As[lc + 0][lr] = av.x; As[lc + 1][lr] = av.y; As[lc + 2][lr] = av.z; As[lc + 3][lr] = av.w;
        *(float4*)&Bs[t >> 4][(t & 15) * 4] = bv;
        __syncthreads();
#pragma unroll
        for (int kk = 0; kk < 16; ++kk) {
            float4 a4 = *(const float4*)&As[kk][ty * 4];
            float4 b4 = *(const float4*)&Bs[kk][tx * 4];
            float ar[4] = {a4.x, a4.y, a4.z, a4.w};
            float br[4] = {b4.x, b4.y, b4.z, b4.w};
#pragma unroll
            for (int i = 0; i < 4; ++i)
#pragma unroll
                for (int j = 0; j < 4; ++j) acc[i][j] += ar[i] * br[j];
        }
    }

#pragma unroll
    for (int i = 0; i < 4; ++i) {
        float4 o;
        o.x = acc[i][0]; o.y = acc[i][1]; o.z = acc[i][2]; o.w = acc[i][3];
        *(float4*)&C[(size_t)(m0 + ty * 4 + i) * DMODEL + n0 + tx * 4] = o;
    }
}

extern "C" void kernel_launch(void* const* d_in, const int* in_sizes, int n_in,
                              void* d_out, int out_size, void* d_ws, size_t ws_size,
                              hipStream_t stream) {
    const float* q  = (const float*)d_in[0];
    const float* k  = (const float*)d_in[1];
    const float* v  = (const float*)d_in[2];
    const float* Wq = (const float*)d_in[3];
    const float* bq = (const float*)d_in[4];
    const float* Wk = (const float*)d_in[5];
    const float* bk = (const float*)d_in[6];

    float* out  = (float*)d_out;                 // [8,1024,768]
    float* attn = out + OUT_ELEMS;               // [8,1024,1024]
    unsigned short* ws = (unsigned short*)d_ws;  // Qhi|Qlo|Khi|Klo bf16 planes (50 MB)

    // 1) Q/K projections into split-bf16 head layout
    hipLaunchKernelGGL(proj_kernel, dim3(12, 128, 2), dim3(256), 0, stream,
                       q, k, Wq, bq, Wk, bk, ws);
    // 2) fused MFMA scores + sparsemax + head-mean -> attn output
    hipLaunchKernelGGL(attn_kernel, dim3(64, 8), dim3(256), 0, stream,
                       ws, attn);
    // 3) output = attn @ v
    hipLaunchKernelGGL(out_gemm, dim3(12, 16, 8), dim3(256), 0, stream,
                       attn, v, out);
}

// Round 3
// 600.288 us; speedup vs baseline: 2.4261x; 1.4271x over previous
//
#include <hip/hip_runtime.h>

// Problem constants
#define BSZ 8
#define NH 12
#define LSEQ 1024
#define DMODEL 768
#define DHEAD 64
#define OUT_ELEMS 6291456   // 8*1024*768
#define ATTN_ELEMS 8388608  // 8*1024*1024

typedef __attribute__((ext_vector_type(8))) short short8;   // 8 x bf16 (4 VGPRs)
typedef __attribute__((ext_vector_type(4))) float f32x4;

__device__ __forceinline__ float wred(float v) {
    v += __shfl_xor(v, 1);
    v += __shfl_xor(v, 2);
    v += __shfl_xor(v, 4);
    v += __shfl_xor(v, 8);
    v += __shfl_xor(v, 16);
    v += __shfl_xor(v, 32);
    return v;
}

__device__ __forceinline__ unsigned short f2bf(float x) {
    union { float f; unsigned u; } c; c.f = x;
    unsigned r = (c.u + 0x7FFF + ((c.u >> 16) & 1)) >> 16;   // RNE
    return (unsigned short)r;
}
__device__ __forceinline__ float bf2f(unsigned short h) {
    union { float f; unsigned u; } c; c.u = ((unsigned)h) << 16;
    return c.f;
}
__device__ __forceinline__ void split2(float x, unsigned short& h, unsigned short& l) {
    h = f2bf(x);
    l = f2bf(x - bf2f(h));
}

// ---------------------------------------------------------------------------
// proj_mfma: C = A @ W^T + bias via split-bf16 3-pass MFMA.
// A [8192x768] fp32, W [768x768] fp32 row-major [out,in] (so both k-major).
// Output: bf16 hi/lo planes in head layout [B,H,L,64].
// blockIdx.z: 0 -> Q (planes 0,1), 1 -> K (planes 2,3). 128x128 tile, BK=32.
// ---------------------------------------------------------------------------
__global__ __launch_bounds__(256) void proj_mfma(
    const float* __restrict__ qin, const float* __restrict__ kin,
    const float* __restrict__ Wq, const float* __restrict__ bq,
    const float* __restrict__ Wk, const float* __restrict__ bk,
    unsigned short* __restrict__ ws) {
    const float* A; const float* W; const float* bias;
    unsigned short* hi; unsigned short* lo;
    if (blockIdx.z == 0) { A = qin; W = Wq; bias = bq; hi = ws;                lo = ws + OUT_ELEMS; }
    else                 { A = kin; W = Wk; bias = bk; hi = ws + 2*OUT_ELEMS; lo = ws + 3*OUT_ELEMS; }

    __shared__ unsigned short Ah[128][32], Al[128][32];
    __shared__ unsigned short Bh[128][32], Bl[128][32];

    const int t    = threadIdx.x;
    const int lane = t & 63;
    const int w    = t >> 6;
    const int wr   = w >> 1, wc = w & 1;       // 2x2 wave grid, each wave 64x64
    const int mrow = lane & 15, quad = lane >> 4;
    const int m0   = blockIdx.y * 128;
    const int n0   = blockIdx.x * 128;

    const int srow = t >> 3;          // 0..31 staging row base
    const int scol = (t & 7) * 4;     // 0..28 staging col

    f32x4 acc[4][4];
#pragma unroll
    for (int i = 0; i < 4; ++i)
#pragma unroll
        for (int j = 0; j < 4; ++j) acc[i][j] = (f32x4){0.f, 0.f, 0.f, 0.f};

    for (int k0 = 0; k0 < DMODEL; k0 += 32) {
        float4 av[4], wv[4];
#pragma unroll
        for (int i = 0; i < 4; ++i) {
            av[i] = *(const float4*)&A[(size_t)(m0 + srow + i * 32) * DMODEL + k0 + scol];
            wv[i] = *(const float4*)&W[(size_t)(n0 + srow + i * 32) * DMODEL + k0 + scol];
        }
        __syncthreads();   // prev step's frag reads done
#pragma unroll
        for (int i = 0; i < 4; ++i) {
            ushort4 h4, l4;
            split2(av[i].x, h4.x, l4.x); split2(av[i].y, h4.y, l4.y);
            split2(av[i].z, h4.z, l4.z); split2(av[i].w, h4.w, l4.w);
            *(ushort4*)&Ah[srow + i * 32][scol] = h4;
            *(ushort4*)&Al[srow + i * 32][scol] = l4;
            split2(wv[i].x, h4.x, l4.x); split2(wv[i].y, h4.y, l4.y);
            split2(wv[i].z, h4.z, l4.z); split2(wv[i].w, h4.w, l4.w);
            *(ushort4*)&Bh[srow + i * 32][scol] = h4;
            *(ushort4*)&Bl[srow + i * 32][scol] = l4;
        }
        __syncthreads();

        short8 ah[4], al[4], bh[4], bl[4];
#pragma unroll
        for (int i = 0; i < 4; ++i) {
            ah[i] = *(const short8*)&Ah[wr * 64 + i * 16 + mrow][quad * 8];
            al[i] = *(const short8*)&Al[wr * 64 + i * 16 + mrow][quad * 8];
            bh[i] = *(const short8*)&Bh[wc * 64 + i * 16 + mrow][quad * 8];
            bl[i] = *(const short8*)&Bl[wc * 64 + i * 16 + mrow][quad * 8];
        }
#pragma unroll
        for (int i = 0; i < 4; ++i)
#pragma unroll
            for (int j = 0; j < 4; ++j) {
                acc[i][j] = __builtin_amdgcn_mfma_f32_16x16x32_bf16(al[i], bh[j], acc[i][j], 0, 0, 0);
                acc[i][j] = __builtin_amdgcn_mfma_f32_16x16x32_bf16(ah[i], bl[j], acc[i][j], 0, 0, 0);
                acc[i][j] = __builtin_amdgcn_mfma_f32_16x16x32_bf16(ah[i], bh[j], acc[i][j], 0, 0, 0);
            }
    }

    // Epilogue: bias add, split to hi/lo, scatter to head layout.
    // D layout per 16x16 tile: m = quad*4 + reg, n = mrow  [R2-verified]
#pragma unroll
    for (int j = 0; j < 4; ++j) {
        const int ng = n0 + wc * 64 + j * 16 + mrow;
        const float bj = bias[ng];
        const int hh = ng >> 6, dd = ng & 63;
#pragma unroll
        for (int i = 0; i < 4; ++i) {
#pragma unroll
            for (int reg = 0; reg < 4; ++reg) {
                const int mg = m0 + wr * 64 + i * 16 + quad * 4 + reg;
                const float c = acc[i][j][reg] + bj;
                unsigned short ch, cl;
                split2(c, ch, cl);
                const size_t idx = (((size_t)(mg >> 10) * NH + hh) * LSEQ + (mg & 1023)) * DHEAD + dd;
                hi[idx] = ch;
                lo[idx] = cl;
            }
        }
    }
}

// ---------------------------------------------------------------------------
// Fused scores (split-bf16 MFMA) + sparsemax + head-mean. UNCHANGED from R2.
// ---------------------------------------------------------------------------
__global__ __launch_bounds__(256, 2) void attn_kernel(
    const unsigned short* __restrict__ ws, float* __restrict__ attn_out) {
    __shared__ float S[16 * 1024];    // 64 KB score tile

    const unsigned short* Qhi = ws;
    const unsigned short* Qlo = ws + OUT_ELEMS;
    const unsigned short* Khi = ws + 2 * OUT_ELEMS;
    const unsigned short* Klo = ws + 3 * OUT_ELEMS;

    const int t = threadIdx.x;
    const int lane = t & 63;
    const int w = t >> 6;
    const int b = blockIdx.y;
    const int q0 = blockIdx.x * 16;

    const int mrow = lane & 15;
    const int quad = lane >> 4;

    f32x4 acc[16];
#pragma unroll
    for (int j = 0; j < 16; ++j) acc[j] = (f32x4){0.f, 0.f, 0.f, 0.f};

    for (int h = 0; h < NH; ++h) {
        const size_t hb = ((size_t)b * NH + h) * (LSEQ * DHEAD);

        const size_t aoff = hb + (size_t)(q0 + mrow) * DHEAD + quad * 8;
        short8 ah0 = *(const short8*)(Qhi + aoff);
        short8 ah1 = *(const short8*)(Qhi + aoff + 32);
        short8 al0 = *(const short8*)(Qlo + aoff);
        short8 al1 = *(const short8*)(Qlo + aoff + 32);

        __syncthreads();

#pragma unroll 4
        for (int nt = 0; nt < 16; ++nt) {
            const int n0 = w * 256 + nt * 16;
            const size_t boff = hb + (size_t)(n0 + mrow) * DHEAD + quad * 8;
            short8 bh0 = *(const short8*)(Khi + boff);
            short8 bh1 = *(const short8*)(Khi + boff + 32);
            short8 bl0 = *(const short8*)(Klo + boff);
            short8 bl1 = *(const short8*)(Klo + boff + 32);
            f32x4 d = {0.f, 0.f, 0.f, 0.f};
            d = __builtin_amdgcn_mfma_f32_16x16x32_bf16(al0, bh0, d, 0, 0, 0);
            d = __builtin_amdgcn_mfma_f32_16x16x32_bf16(ah0, bl0, d, 0, 0, 0);
            d = __builtin_amdgcn_mfma_f32_16x16x32_bf16(ah0, bh0, d, 0, 0, 0);
            d = __builtin_amdgcn_mfma_f32_16x16x32_bf16(al1, bh1, d, 0, 0, 0);
            d = __builtin_amdgcn_mfma_f32_16x16x32_bf16(ah1, bl1, d, 0, 0, 0);
            d = __builtin_amdgcn_mfma_f32_16x16x32_bf16(ah1, bh1, d, 0, 0, 0);
#pragma unroll
            for (int reg = 0; reg < 4; ++reg)
                S[(quad * 4 + reg) * 1024 + n0 + mrow] = d[reg] * 0.125f;
        }
        __syncthreads();

#pragma unroll
        for (int rr = 0; rr < 4; ++rr) {
            const int r = w * 4 + rr;
            float z[16];
#pragma unroll
            for (int j = 0; j < 16; ++j) z[j] = S[r * 1024 + lane + 64 * j];
            float s0 = 0.f;
#pragma unroll
            for (int j = 0; j < 16; ++j) s0 += z[j];
            float tau = (wred(s0) - 1.0f) * (1.0f / 1024.0f);
            float prev = 1024.0f;
            for (int it = 0; it < 64; ++it) {
                float s = 0.f, c2 = 0.f;
#pragma unroll
                for (int j = 0; j < 16; ++j) {
                    if (z[j] > tau) { s += z[j]; c2 += 1.0f; }
                }
                s = wred(s); c2 = wred(c2);
                if (c2 == prev) break;
                tau = (s - 1.0f) / c2;
                prev = c2;
            }
#pragma unroll
            for (int j = 0; j < 16; ++j) {
                float p = z[j] - tau;
                S[r * 1024 + lane + 64 * j] = p > 0.f ? p : 0.f;
            }
        }
        __syncthreads();

#pragma unroll
        for (int j = 0; j < 16; ++j) {
            f32x4 vv = *(const f32x4*)&S[j * 1024 + t * 4];
            acc[j] += vv;
        }
    }

    float* ao = attn_out + ((size_t)b * LSEQ + q0) * LSEQ;
#pragma unroll
    for (int j = 0; j < 16; ++j) {
        f32x4 o = acc[j] * (1.0f / 12.0f);
        *(f32x4*)&ao[(size_t)j * LSEQ + t * 4] = o;
    }
}

// ---------------------------------------------------------------------------
// out_mfma: out[b] = attn[b] @ v[b] via split-bf16 3-pass MFMA.
// attn [1024x1024] fp32 (k-major rows), v [1024x768] fp32 (n-major rows ->
// staged transposed into LDS [n][k], row stride 36 to kill bank conflicts).
// 128x128 tile, BK=32.
// ---------------------------------------------------------------------------
__global__ __launch_bounds__(256) void out_mfma(
    const float* __restrict__ attn, const float* __restrict__ v,
    float* __restrict__ out) {
    const int b = blockIdx.z;
    const float* Ab = attn + (size_t)b * LSEQ * LSEQ;
    const float* Vb = v    + (size_t)b * LSEQ * DMODEL;
    float* Cb       = out  + (size_t)b * LSEQ * DMODEL;

    __shared__ unsigned short Ah[128][32], Al[128][32];
    __shared__ unsigned short Bh[128][36], Bl[128][36];   // pad 36: conflict-free 8B rd/wr

    const int t    = threadIdx.x;
    const int lane = t & 63;
    const int w    = t >> 6;
    const int wr   = w >> 1, wc = w & 1;
    const int mrow = lane & 15, quad = lane >> 4;
    const int m0   = blockIdx.y * 128;
    const int n0   = blockIdx.x * 128;

    const int srow = t >> 3;
    const int scol = (t & 7) * 4;
    const int bn   = t & 127;          // transpose-staging column
    const int bk0  = (t >> 7) * 16;    // transpose-staging k base

    f32x4 acc[4][4];
#pragma unroll
    for (int i = 0; i < 4; ++i)
#pragma unroll
        for (int j = 0; j < 4; ++j) acc[i][j] = (f32x4){0.f, 0.f, 0.f, 0.f};

    for (int k0 = 0; k0 < LSEQ; k0 += 32) {
        float4 av[4];
#pragma unroll
        for (int i = 0; i < 4; ++i)
            av[i] = *(const float4*)&Ab[(size_t)(m0 + srow + i * 32) * LSEQ + k0 + scol];
        float bv[16];
#pragma unroll
        for (int i = 0; i < 16; ++i)
            bv[i] = Vb[(size_t)(k0 + bk0 + i) * DMODEL + n0 + bn];

        __syncthreads();
#pragma unroll
        for (int i = 0; i < 4; ++i) {
            ushort4 h4, l4;
            split2(av[i].x, h4.x, l4.x); split2(av[i].y, h4.y, l4.y);
            split2(av[i].z, h4.z, l4.z); split2(av[i].w, h4.w, l4.w);
            *(ushort4*)&Ah[srow + i * 32][scol] = h4;
            *(ushort4*)&Al[srow + i * 32][scol] = l4;
        }
#pragma unroll
        for (int g = 0; g < 4; ++g) {
            ushort4 h4, l4;
            split2(bv[g * 4 + 0], h4.x, l4.x); split2(bv[g * 4 + 1], h4.y, l4.y);
            split2(bv[g * 4 + 2], h4.z, l4.z); split2(bv[g * 4 + 3], h4.w, l4.w);
            *(ushort4*)&Bh[bn][bk0 + g * 4] = h4;
            *(ushort4*)&Bl[bn][bk0 + g * 4] = l4;
        }
        __syncthreads();

        short8 ah[4], al[4], bh[4], bl[4];
#pragma unroll
        for (int i = 0; i < 4; ++i) {
            ah[i] = *(const short8*)&Ah[wr * 64 + i * 16 + mrow][quad * 8];
            al[i] = *(const short8*)&Al[wr * 64 + i * 16 + mrow][quad * 8];
        }
#pragma unroll
        for (int j = 0; j < 4; ++j) {
            // row stride 36 ushorts = 72 B: not 16B-aligned -> assemble from 2x8B
            const unsigned short* ph = &Bh[wc * 64 + j * 16 + mrow][quad * 8];
            const unsigned short* pl = &Bl[wc * 64 + j * 16 + mrow][quad * 8];
            uint2 h0 = *(const uint2*)ph;
            uint2 h1 = *(const uint2*)(ph + 4);
            uint2 l0 = *(const uint2*)pl;
            uint2 l1 = *(const uint2*)(pl + 4);
            union { uint u[4]; short8 s; } ch, cl;
            ch.u[0] = h0.x; ch.u[1] = h0.y; ch.u[2] = h1.x; ch.u[3] = h1.y;
            cl.u[0] = l0.x; cl.u[1] = l0.y; cl.u[2] = l1.x; cl.u[3] = l1.y;
            bh[j] = ch.s; bl[j] = cl.s;
        }
#pragma unroll
        for (int i = 0; i < 4; ++i)
#pragma unroll
            for (int j = 0; j < 4; ++j) {
                acc[i][j] = __builtin_amdgcn_mfma_f32_16x16x32_bf16(al[i], bh[j], acc[i][j], 0, 0, 0);
                acc[i][j] = __builtin_amdgcn_mfma_f32_16x16x32_bf16(ah[i], bl[j], acc[i][j], 0, 0, 0);
                acc[i][j] = __builtin_amdgcn_mfma_f32_16x16x32_bf16(ah[i], bh[j], acc[i][j], 0, 0, 0);
            }
    }

#pragma unroll
    for (int i = 0; i < 4; ++i)
#pragma unroll
        for (int j = 0; j < 4; ++j)
#pragma unroll
            for (int reg = 0; reg < 4; ++reg) {
                const int mg = m0 + wr * 64 + i * 16 + quad * 4 + reg;
                const int ng = n0 + wc * 64 + j * 16 + mrow;
                Cb[(size_t)mg * DMODEL + ng] = acc[i][j][reg];
            }
}

extern "C" void kernel_launch(void* const* d_in, const int* in_sizes, int n_in,
                              void* d_out, int out_size, void* d_ws, size_t ws_size,
                              hipStream_t stream) {
    const float* q  = (const float*)d_in[0];
    const float* k  = (const float*)d_in[1];
    const float* v  = (const float*)d_in[2];
    const float* Wq = (const float*)d_in[3];
    const float* bq = (const float*)d_in[4];
    const float* Wk = (const float*)d_in[5];
    const float* bk = (const float*)d_in[6];

    float* out  = (float*)d_out;                 // [8,1024,768]
    float* attn = out + OUT_ELEMS;               // [8,1024,1024]
    unsigned short* ws = (unsigned short*)d_ws;  // Qhi|Qlo|Khi|Klo bf16 planes (50 MB)

    // 1) Q/K projections (MFMA) into split-bf16 head layout
    hipLaunchKernelGGL(proj_mfma, dim3(6, 64, 2), dim3(256), 0, stream,
                       q, k, Wq, bq, Wk, bk, ws);
    // 2) fused MFMA scores + sparsemax + head-mean -> attn output
    hipLaunchKernelGGL(attn_kernel, dim3(64, 8), dim3(256), 0, stream,
                       ws, attn);
    // 3) output = attn @ v (MFMA)
    hipLaunchKernelGGL(out_mfma, dim3(6, 8, 8), dim3(256), 0, stream,
                       attn, v, out);
}

// Round 4
// 553.979 us; speedup vs baseline: 2.6289x; 1.0836x over previous
//
#include <hip/hip_runtime.h>

// Problem constants
#define BSZ 8
#define NH 12
#define LSEQ 1024
#define DMODEL 768
#define DHEAD 64
#define OUT_ELEMS 6291456   // 8*1024*768
#define ATTN_ELEMS 8388608  // 8*1024*1024

typedef __attribute__((ext_vector_type(8))) short short8;   // 8 x bf16 (4 VGPRs)
typedef __attribute__((ext_vector_type(4))) float f32x4;

__device__ __forceinline__ int   f2i(float x) { union { float f; int i; } c; c.f = x; return c.i; }
__device__ __forceinline__ float i2f(int x)   { union { int i; float f; } c; c.i = x; return c.f; }

__device__ __forceinline__ unsigned short f2bf(float x) {
    union { float f; unsigned u; } c; c.f = x;
    unsigned r = (c.u + 0x7FFF + ((c.u >> 16) & 1)) >> 16;   // RNE
    return (unsigned short)r;
}
__device__ __forceinline__ float bf2f(unsigned short h) {
    union { float f; unsigned u; } c; c.u = ((unsigned)h) << 16;
    return c.f;
}
__device__ __forceinline__ void split2(float x, unsigned short& h, unsigned short& l) {
    h = f2bf(x);
    l = f2bf(x - bf2f(h));
}

// ---- DPP wave-64 reductions (result valid in lane 63, broadcast via readlane) ----
template<int CTRL>
__device__ __forceinline__ float dppadd(float v) {
    return v + i2f(__builtin_amdgcn_update_dpp(0, f2i(v), CTRL, 0xF, 0xF, true));
}
template<int CTRL>
__device__ __forceinline__ float dppmax(float v) {
    return fmaxf(v, i2f(__builtin_amdgcn_update_dpp(f2i(v), f2i(v), CTRL, 0xF, 0xF, false)));
}

// 4 interleaved sum chains -> each s[rr] becomes wave-total (uniform)
__device__ __forceinline__ void wsum4(float s[4]) {
#define WS(CTRL) _Pragma("unroll") for (int rr = 0; rr < 4; ++rr) { s[rr] = dppadd<CTRL>(s[rr]); }
    WS(0x111) WS(0x112) WS(0x114) WS(0x118) WS(0x142) WS(0x143)
#undef WS
#pragma unroll
    for (int rr = 0; rr < 4; ++rr) s[rr] = i2f(__builtin_amdgcn_readlane(f2i(s[rr]), 63));
}

// 4 sum + 4 max interleaved chains
__device__ __forceinline__ void wsummax4(float s[4], float m[4]) {
#define WS(CTRL) _Pragma("unroll") for (int rr = 0; rr < 4; ++rr) { s[rr] = dppadd<CTRL>(s[rr]); m[rr] = dppmax<CTRL>(m[rr]); }
    WS(0x111) WS(0x112) WS(0x114) WS(0x118) WS(0x142) WS(0x143)
#undef WS
#pragma unroll
    for (int rr = 0; rr < 4; ++rr) {
        s[rr] = i2f(__builtin_amdgcn_readlane(f2i(s[rr]), 63));
        m[rr] = i2f(__builtin_amdgcn_readlane(f2i(m[rr]), 63));
    }
}

// ---------------------------------------------------------------------------
// proj_mfma: C = A @ W^T + bias via split-bf16 3-pass MFMA. UNCHANGED from R3.
// ---------------------------------------------------------------------------
__global__ __launch_bounds__(256) void proj_mfma(
    const float* __restrict__ qin, const float* __restrict__ kin,
    const float* __restrict__ Wq, const float* __restrict__ bq,
    const float* __restrict__ Wk, const float* __restrict__ bk,
    unsigned short* __restrict__ ws) {
    const float* A; const float* W; const float* bias;
    unsigned short* hi; unsigned short* lo;
    if (blockIdx.z == 0) { A = qin; W = Wq; bias = bq; hi = ws;                lo = ws + OUT_ELEMS; }
    else                 { A = kin; W = Wk; bias = bk; hi = ws + 2*OUT_ELEMS; lo = ws + 3*OUT_ELEMS; }

    __shared__ unsigned short Ah[128][32], Al[128][32];
    __shared__ unsigned short Bh[128][32], Bl[128][32];

    const int t    = threadIdx.x;
    const int lane = t & 63;
    const int w    = t >> 6;
    const int wr   = w >> 1, wc = w & 1;
    const int mrow = lane & 15, quad = lane >> 4;
    const int m0   = blockIdx.y * 128;
    const int n0   = blockIdx.x * 128;

    const int srow = t >> 3;
    const int scol = (t & 7) * 4;

    f32x4 acc[4][4];
#pragma unroll
    for (int i = 0; i < 4; ++i)
#pragma unroll
        for (int j = 0; j < 4; ++j) acc[i][j] = (f32x4){0.f, 0.f, 0.f, 0.f};

    for (int k0 = 0; k0 < DMODEL; k0 += 32) {
        float4 av[4], wv[4];
#pragma unroll
        for (int i = 0; i < 4; ++i) {
            av[i] = *(const float4*)&A[(size_t)(m0 + srow + i * 32) * DMODEL + k0 + scol];
            wv[i] = *(const float4*)&W[(size_t)(n0 + srow + i * 32) * DMODEL + k0 + scol];
        }
        __syncthreads();
#pragma unroll
        for (int i = 0; i < 4; ++i) {
            ushort4 h4, l4;
            split2(av[i].x, h4.x, l4.x); split2(av[i].y, h4.y, l4.y);
            split2(av[i].z, h4.z, l4.z); split2(av[i].w, h4.w, l4.w);
            *(ushort4*)&Ah[srow + i * 32][scol] = h4;
            *(ushort4*)&Al[srow + i * 32][scol] = l4;
            split2(wv[i].x, h4.x, l4.x); split2(wv[i].y, h4.y, l4.y);
            split2(wv[i].z, h4.z, l4.z); split2(wv[i].w, h4.w, l4.w);
            *(ushort4*)&Bh[srow + i * 32][scol] = h4;
            *(ushort4*)&Bl[srow + i * 32][scol] = l4;
        }
        __syncthreads();

        short8 ah[4], al[4], bh[4], bl[4];
#pragma unroll
        for (int i = 0; i < 4; ++i) {
            ah[i] = *(const short8*)&Ah[wr * 64 + i * 16 + mrow][quad * 8];
            al[i] = *(const short8*)&Al[wr * 64 + i * 16 + mrow][quad * 8];
            bh[i] = *(const short8*)&Bh[wc * 64 + i * 16 + mrow][quad * 8];
            bl[i] = *(const short8*)&Bl[wc * 64 + i * 16 + mrow][quad * 8];
        }
#pragma unroll
        for (int i = 0; i < 4; ++i)
#pragma unroll
            for (int j = 0; j < 4; ++j) {
                acc[i][j] = __builtin_amdgcn_mfma_f32_16x16x32_bf16(al[i], bh[j], acc[i][j], 0, 0, 0);
                acc[i][j] = __builtin_amdgcn_mfma_f32_16x16x32_bf16(ah[i], bl[j], acc[i][j], 0, 0, 0);
                acc[i][j] = __builtin_amdgcn_mfma_f32_16x16x32_bf16(ah[i], bh[j], acc[i][j], 0, 0, 0);
            }
    }

#pragma unroll
    for (int j = 0; j < 4; ++j) {
        const int ng = n0 + wc * 64 + j * 16 + mrow;
        const float bj = bias[ng];
        const int hh = ng >> 6, dd = ng & 63;
#pragma unroll
        for (int i = 0; i < 4; ++i) {
#pragma unroll
            for (int reg = 0; reg < 4; ++reg) {
                const int mg = m0 + wr * 64 + i * 16 + quad * 4 + reg;
                const float c = acc[i][j][reg] + bj;
                unsigned short ch, cl;
                split2(c, ch, cl);
                const size_t idx = (((size_t)(mg >> 10) * NH + hh) * LSEQ + (mg & 1023)) * DHEAD + dd;
                hi[idx] = ch;
                lo[idx] = cl;
            }
        }
    }
}

// ---------------------------------------------------------------------------
// Fused scores (split-bf16 MFMA) + sparsemax + head-mean.
// R4: sparsemax rebuilt — DPP reductions, 4 rows in lockstep, ballot-based
// support count, warm-start tau0 = max((sum-1)/K, zmax-1) (both provable
// lower bounds of tau*; Michelot invariant S0 >= S* preserved -> exact).
// ---------------------------------------------------------------------------
__global__ __launch_bounds__(256, 2) void attn_kernel(
    const unsigned short* __restrict__ ws, float* __restrict__ attn_out) {
    __shared__ float S[16 * 1024];    // 64 KB score tile

    const unsigned short* Qhi = ws;
    const unsigned short* Qlo = ws + OUT_ELEMS;
    const unsigned short* Khi = ws + 2 * OUT_ELEMS;
    const unsigned short* Klo = ws + 3 * OUT_ELEMS;

    const int t = threadIdx.x;
    const int lane = t & 63;
    const int w = t >> 6;
    const int b = blockIdx.y;
    const int q0 = blockIdx.x * 16;

    const int mrow = lane & 15;
    const int quad = lane >> 4;

    f32x4 acc[16];
#pragma unroll
    for (int j = 0; j < 16; ++j) acc[j] = (f32x4){0.f, 0.f, 0.f, 0.f};

    for (int h = 0; h < NH; ++h) {
        const size_t hb = ((size_t)b * NH + h) * (LSEQ * DHEAD);

        const size_t aoff = hb + (size_t)(q0 + mrow) * DHEAD + quad * 8;
        short8 ah0 = *(const short8*)(Qhi + aoff);
        short8 ah1 = *(const short8*)(Qhi + aoff + 32);
        short8 al0 = *(const short8*)(Qlo + aoff);
        short8 al1 = *(const short8*)(Qlo + aoff + 32);

        __syncthreads();   // previous head's S reads complete before overwrite

#pragma unroll 4
        for (int nt = 0; nt < 16; ++nt) {
            const int n0 = w * 256 + nt * 16;
            const size_t boff = hb + (size_t)(n0 + mrow) * DHEAD + quad * 8;
            short8 bh0 = *(const short8*)(Khi + boff);
            short8 bh1 = *(const short8*)(Khi + boff + 32);
            short8 bl0 = *(const short8*)(Klo + boff);
            short8 bl1 = *(const short8*)(Klo + boff + 32);
            f32x4 d = {0.f, 0.f, 0.f, 0.f};
            d = __builtin_amdgcn_mfma_f32_16x16x32_bf16(al0, bh0, d, 0, 0, 0);
            d = __builtin_amdgcn_mfma_f32_16x16x32_bf16(ah0, bl0, d, 0, 0, 0);
            d = __builtin_amdgcn_mfma_f32_16x16x32_bf16(ah0, bh0, d, 0, 0, 0);
            d = __builtin_amdgcn_mfma_f32_16x16x32_bf16(al1, bh1, d, 0, 0, 0);
            d = __builtin_amdgcn_mfma_f32_16x16x32_bf16(ah1, bl1, d, 0, 0, 0);
            d = __builtin_amdgcn_mfma_f32_16x16x32_bf16(ah1, bh1, d, 0, 0, 0);
#pragma unroll
            for (int reg = 0; reg < 4; ++reg)
                S[(quad * 4 + reg) * 1024 + n0 + mrow] = d[reg] * 0.125f;
        }
        __syncthreads();

        // ---- sparsemax: wave w owns rows 4w..4w+3, iterated in lockstep ----
        {
            float z[4][16];
            float sv[4], mv[4];
#pragma unroll
            for (int rr = 0; rr < 4; ++rr) {
                const int r = w * 4 + rr;
#pragma unroll
                for (int c = 0; c < 4; ++c)   // lane-contiguous b128: conflict-free
                    *(f32x4*)&z[rr][c * 4] = *(const f32x4*)&S[r * 1024 + c * 256 + lane * 4];
                float s = 0.f, m = z[rr][0];
#pragma unroll
                for (int j = 0; j < 16; ++j) s += z[rr][j];
#pragma unroll
                for (int j = 1; j < 16; ++j) m = fmaxf(m, z[rr][j]);
                sv[rr] = s; mv[rr] = m;
            }
            wsummax4(sv, mv);

            float tau[4]; int prev[4]; bool done[4];
#pragma unroll
            for (int rr = 0; rr < 4; ++rr) {
                tau[rr] = fmaxf((sv[rr] - 1.0f) * (1.0f / 1024.0f), mv[rr] - 1.0f);
                prev[rr] = -1; done[rr] = false;
            }

            for (int it = 0; it < 64; ++it) {
                float s4[4]; int c4[4];
#pragma unroll
                for (int rr = 0; rr < 4; ++rr) {
                    float s = 0.f; int c = 0;
#pragma unroll
                    for (int j = 0; j < 16; ++j) {
                        bool gt = z[rr][j] > tau[rr];
                        c += __popcll(__ballot(gt));          // scalar-pipe count
                        s += gt ? z[rr][j] : 0.f;
                    }
                    s4[rr] = s; c4[rr] = c;
                }
                wsum4(s4);
                bool alldone = true;
#pragma unroll
                for (int rr = 0; rr < 4; ++rr) {
                    if (!done[rr]) {
                        if (c4[rr] == prev[rr]) done[rr] = true;
                        else { tau[rr] = (s4[rr] - 1.0f) / (float)c4[rr]; prev[rr] = c4[rr]; }
                    }
                    alldone = alldone && done[rr];
                }
                if (alldone) break;
            }

#pragma unroll
            for (int rr = 0; rr < 4; ++rr) {
                const int r = w * 4 + rr;
#pragma unroll
                for (int c = 0; c < 4; ++c) {
                    f32x4 p;
#pragma unroll
                    for (int j = 0; j < 4; ++j)
                        p[j] = fmaxf(z[rr][c * 4 + j] - tau[rr], 0.f);
                    *(f32x4*)&S[r * 1024 + c * 256 + lane * 4] = p;
                }
            }
        }
        __syncthreads();

        // head-mean accumulate: thread t owns float4-column t across all 16 rows
#pragma unroll
        for (int j = 0; j < 16; ++j) {
            f32x4 vv = *(const f32x4*)&S[j * 1024 + t * 4];
            acc[j] += vv;
        }
    }

    float* ao = attn_out + ((size_t)b * LSEQ + q0) * LSEQ;
#pragma unroll
    for (int j = 0; j < 16; ++j) {
        f32x4 o = acc[j] * (1.0f / 12.0f);
        *(f32x4*)&ao[(size_t)j * LSEQ + t * 4] = o;
    }
}

// ---------------------------------------------------------------------------
// out_mfma: out[b] = attn[b] @ v[b] via split-bf16 3-pass MFMA. UNCHANGED.
// ---------------------------------------------------------------------------
__global__ __launch_bounds__(256) void out_mfma(
    const float* __restrict__ attn, const float* __restrict__ v,
    float* __restrict__ out) {
    const int b = blockIdx.z;
    const float* Ab = attn + (size_t)b * LSEQ * LSEQ;
    const float* Vb = v    + (size_t)b * LSEQ * DMODEL;
    float* Cb       = out  + (size_t)b * LSEQ * DMODEL;

    __shared__ unsigned short Ah[128][32], Al[128][32];
    __shared__ unsigned short Bh[128][36], Bl[128][36];   // pad 36: conflict-free 8B rd/wr

    const int t    = threadIdx.x;
    const int lane = t & 63;
    const int w    = t >> 6;
    const int wr   = w >> 1, wc = w & 1;
    const int mrow = lane & 15, quad = lane >> 4;
    const int m0   = blockIdx.y * 128;
    const int n0   = blockIdx.x * 128;

    const int srow = t >> 3;
    const int scol = (t & 7) * 4;
    const int bn   = t & 127;
    const int bk0  = (t >> 7) * 16;

    f32x4 acc[4][4];
#pragma unroll
    for (int i = 0; i < 4; ++i)
#pragma unroll
        for (int j = 0; j < 4; ++j) acc[i][j] = (f32x4){0.f, 0.f, 0.f, 0.f};

    for (int k0 = 0; k0 < LSEQ; k0 += 32) {
        float4 av[4];
#pragma unroll
        for (int i = 0; i < 4; ++i)
            av[i] = *(const float4*)&Ab[(size_t)(m0 + srow + i * 32) * LSEQ + k0 + scol];
        float bv[16];
#pragma unroll
        for (int i = 0; i < 16; ++i)
            bv[i] = Vb[(size_t)(k0 + bk0 + i) * DMODEL + n0 + bn];

        __syncthreads();
#pragma unroll
        for (int i = 0; i < 4; ++i) {
            ushort4 h4, l4;
            split2(av[i].x, h4.x, l4.x); split2(av[i].y, h4.y, l4.y);
            split2(av[i].z, h4.z, l4.z); split2(av[i].w, h4.w, l4.w);
            *(ushort4*)&Ah[srow + i * 32][scol] = h4;
            *(ushort4*)&Al[srow + i * 32][scol] = l4;
        }
#pragma unroll
        for (int g = 0; g < 4; ++g) {
            ushort4 h4, l4;
            split2(bv[g * 4 + 0], h4.x, l4.x); split2(bv[g * 4 + 1], h4.y, l4.y);
            split2(bv[g * 4 + 2], h4.z, l4.z); split2(bv[g * 4 + 3], h4.w, l4.w);
            *(ushort4*)&Bh[bn][bk0 + g * 4] = h4;
            *(ushort4*)&Bl[bn][bk0 + g * 4] = l4;
        }
        __syncthreads();

        short8 ah[4], al[4], bh[4], bl[4];
#pragma unroll
        for (int i = 0; i < 4; ++i) {
            ah[i] = *(const short8*)&Ah[wr * 64 + i * 16 + mrow][quad * 8];
            al[i] = *(const short8*)&Al[wr * 64 + i * 16 + mrow][quad * 8];
        }
#pragma unroll
        for (int j = 0; j < 4; ++j) {
            const unsigned short* ph = &Bh[wc * 64 + j * 16 + mrow][quad * 8];
            const unsigned short* pl = &Bl[wc * 64 + j * 16 + mrow][quad * 8];
            uint2 h0 = *(const uint2*)ph;
            uint2 h1 = *(const uint2*)(ph + 4);
            uint2 l0 = *(const uint2*)pl;
            uint2 l1 = *(const uint2*)(pl + 4);
            union { uint u[4]; short8 s; } ch, cl;
            ch.u[0] = h0.x; ch.u[1] = h0.y; ch.u[2] = h1.x; ch.u[3] = h1.y;
            cl.u[0] = l0.x; cl.u[1] = l0.y; cl.u[2] = l1.x; cl.u[3] = l1.y;
            bh[j] = ch.s; bl[j] = cl.s;
        }
#pragma unroll
        for (int i = 0; i < 4; ++i)
#pragma unroll
            for (int j = 0; j < 4; ++j) {
                acc[i][j] = __builtin_amdgcn_mfma_f32_16x16x32_bf16(al[i], bh[j], acc[i][j], 0, 0, 0);
                acc[i][j] = __builtin_amdgcn_mfma_f32_16x16x32_bf16(ah[i], bl[j], acc[i][j], 0, 0, 0);
                acc[i][j] = __builtin_amdgcn_mfma_f32_16x16x32_bf16(ah[i], bh[j], acc[i][j], 0, 0, 0);
            }
    }

#pragma unroll
    for (int i = 0; i < 4; ++i)
#pragma unroll
        for (int j = 0; j < 4; ++j)
#pragma unroll
            for (int reg = 0; reg < 4; ++reg) {
                const int mg = m0 + wr * 64 + i * 16 + quad * 4 + reg;
                const int ng = n0 + wc * 64 + j * 16 + mrow;
                Cb[(size_t)mg * DMODEL + ng] = acc[i][j][reg];
            }
}

extern "C" void kernel_launch(void* const* d_in, const int* in_sizes, int n_in,
                              void* d_out, int out_size, void* d_ws, size_t ws_size,
                              hipStream_t stream) {
    const float* q  = (const float*)d_in[0];
    const float* k  = (const float*)d_in[1];
    const float* v  = (const float*)d_in[2];
    const float* Wq = (const float*)d_in[3];
    const float* bq = (const float*)d_in[4];
    const float* Wk = (const float*)d_in[5];
    const float* bk = (const float*)d_in[6];

    float* out  = (float*)d_out;                 // [8,1024,768]
    float* attn = out + OUT_ELEMS;               // [8,1024,1024]
    unsigned short* ws = (unsigned short*)d_ws;  // Qhi|Qlo|Khi|Klo bf16 planes (50 MB)

    hipLaunchKernelGGL(proj_mfma, dim3(6, 64, 2), dim3(256), 0, stream,
                       q, k, Wq, bq, Wk, bk, ws);
    hipLaunchKernelGGL(attn_kernel, dim3(64, 8), dim3(256), 0, stream,
                       ws, attn);
    hipLaunchKernelGGL(out_mfma, dim3(6, 8, 8), dim3(256), 0, stream,
                       attn, v, out);
}